// Round 13
// baseline (335.729 us; speedup 1.0000x reference)
//
#include <hip/hip_runtime.h>

#define TTOK   4096
#define DIMK   1024
#define NEXP   8
#define INTERN 1408
#define NPAIRS 8192   // TTOK * TOPK

#define BM  128
#define BN  128
#define BK  64
#define NTH 256       // prep block size
#define NTG 512       // GEMM block size: 8 waves, 2x4 wave grid
#define MAXRT (NPAIRS / BM + NEXP - 1)   // 71 worst-case row tiles
#define NT1  (INTERN / BN)               // 11 n-tiles gemm1
#define NT2  (DIMK / BN)                 // 8 n-tiles gemm2

#define XCVB 512                         // x-convert blocks; +1 block routes
#define N8X (TTOK * DIMK / 8)

typedef __attribute__((ext_vector_type(8))) _Float16 half8;
typedef __attribute__((ext_vector_type(4))) float f32x4;

#define MFMAF16(a, b, c) __builtin_amdgcn_mfma_f32_16x16x32_f16((a), (b), (c), 0, 0, 0)

// async global->LDS, 16B/lane. LDS dest = wave-uniform base + lane*16 (linear);
// swizzle lives in the per-lane GLOBAL source address (m173 pattern).
__device__ __forceinline__ void gl_lds16(const void* g, void* l) {
  __builtin_amdgcn_global_load_lds(
      (const __attribute__((address_space(1))) void*)g,
      (__attribute__((address_space(3))) void*)l, 16, 0, 0);
}

// bijective XCD chunk swizzle (m204)
__device__ __forceinline__ int xcd_swz(int orig, int G) {
  int q = G >> 3, r = G & 7, x = orig & 7, p = orig >> 3;
  return (x < r ? x * (q + 1) : r * (q + 1) + (x - r) * q) + p;
}

// reg-staged fp32->fp16 convert of one 8-elem chunk (32B fp32 -> 16B fp16),
// written to a (swizzled) LDS dest. cvt_pkrtz numerics HW-validated in R10.
__device__ __forceinline__ void stage_cvt8(const float* __restrict__ src,
                                           unsigned short* __restrict__ dst) {
  f32x4 a = *reinterpret_cast<const f32x4*>(src);
  f32x4 b = *reinterpret_cast<const f32x4*>(src + 4);
  uint4 o;
  o.x = __builtin_bit_cast(unsigned int, __builtin_amdgcn_cvt_pkrtz(a[0], a[1]));
  o.y = __builtin_bit_cast(unsigned int, __builtin_amdgcn_cvt_pkrtz(a[2], a[3]));
  o.z = __builtin_bit_cast(unsigned int, __builtin_amdgcn_cvt_pkrtz(b[0], b[1]));
  o.w = __builtin_bit_cast(unsigned int, __builtin_amdgcn_cvt_pkrtz(b[2], b[3]));
  *reinterpret_cast<uint4*>(dst) = o;
}

// --------------- prep: convert x to fp16 (512 blocks) + routing (1 block) ---
__global__ __launch_bounds__(NTH) void prep_kernel(
    const float* __restrict__ x, unsigned short* __restrict__ xf,
    const int* __restrict__ ei, int* __restrict__ offs, int* __restrict__ pairs) {
  const int t = threadIdx.x;

  if (blockIdx.x == XCVB) {
    // ---- routing block ----
    __shared__ int cnt[NEXP], base[NEXP], cur[NEXP], mode;
    if (t == 0) mode = 0;
    if (t < NEXP) cnt[t] = 0;
    __syncthreads();
    // width probe: odd 32-bit words all-zero => int64 input, else int32
    int any = 0;
    for (int i = t; i < NPAIRS / 2; i += NTH) any |= ei[2 * i + 1];
    if (any) atomicOr(&mode, 1);
    __syncthreads();
    const int m32 = mode;
    for (int i = t; i < NPAIRS; i += NTH) {
      int e = (m32 ? ei[i] : ei[2 * i]) & (NEXP - 1);
      atomicAdd(&cnt[e], 1);
    }
    __syncthreads();
    if (t == 0) {
      int s = 0;
      for (int e = 0; e < NEXP; ++e) { base[e] = s; offs[e] = s; s += cnt[e]; }
      offs[NEXP] = s;
    }
    __syncthreads();
    if (t < NEXP) cur[t] = base[t];
    __syncthreads();
    for (int i = t; i < NPAIRS; i += NTH) {
      int e = (m32 ? ei[i] : ei[2 * i]) & (NEXP - 1);
      int p = atomicAdd(&cur[e], 1);
      pairs[p] = i;   // pair id: token = i>>1, out row = i
    }
    return;
  }

  // ---- x convert: 4 iters/thread, 2x16B load -> 16B store ----
  const int tid = blockIdx.x * NTH + t;
  const int stride = XCVB * NTH;
  const f32x4* s4 = reinterpret_cast<const f32x4*>(x);
  uint4* d4 = reinterpret_cast<uint4*>(xf);
  for (int i = tid; i < N8X; i += stride) {
    f32x4 a = s4[2 * i], b = s4[2 * i + 1];
    uint4 o;
    o.x = __builtin_bit_cast(unsigned int, __builtin_amdgcn_cvt_pkrtz(a[0], a[1]));
    o.y = __builtin_bit_cast(unsigned int, __builtin_amdgcn_cvt_pkrtz(a[2], a[3]));
    o.z = __builtin_bit_cast(unsigned int, __builtin_amdgcn_cvt_pkrtz(b[0], b[1]));
    o.w = __builtin_bit_cast(unsigned int, __builtin_amdgcn_cvt_pkrtz(b[2], b[3]));
    d4[i] = o;
  }
}

// ------------------------------------------------------------ tile lookup ---
__device__ __forceinline__ bool find_tile(const int* __restrict__ offs, int rt,
                                          int &e, int &row0, int &row_end) {
  int cum = 0;
  for (int i = 0; i < NEXP; ++i) {
    int b = offs[i], en = offs[i + 1];
    int nt = (en - b + BM - 1) / BM;
    if (rt < cum + nt) { e = i; row0 = b + (rt - cum) * BM; row_end = en; return true; }
    cum += nt;
  }
  return false;
}

// -------------------------------------------------- GEMM1: x @ w1/w3, SiLU ---
// A (x, fp16): gl_lds with pre-swizzled source (R8-verified, 0 conflicts).
// B (w1/w3, fp32): reg-staged with fused cvt_pkrtz + swizzled ds_write — the
// conversion that used to be the 76us prep pass now hides under MFMA.
__global__ __launch_bounds__(NTG, 4) void gemm1_kernel(
    const unsigned short* __restrict__ xf, const float* __restrict__ w1,
    const float* __restrict__ w3, const int* __restrict__ offs,
    const int* __restrict__ pairs, unsigned short* __restrict__ hf) {
  __shared__ __align__(16) unsigned short At[BM * BK];
  __shared__ __align__(16) unsigned short B1t[BN * BK];
  __shared__ __align__(16) unsigned short B3t[BN * BK];

  const int lid = xcd_swz((int)blockIdx.x, MAXRT * NT1);
  const int rt = lid % MAXRT, nt = lid / MAXRT;   // rt fastest: XCD sweeps row
  int e, row0, row_end;                           // tiles vs L2-hot W slice
  if (!find_tile(offs, rt, e, row0, row_end)) return;
  const int n0 = nt * BN;
  const int t = threadIdx.x;
  const int ln = t & 63;
  const int wv = t >> 6;                 // wave 0..7
  const int wm = wv >> 2, wn = wv & 3;   // 2x4 wave grid over 128x128 out
  const int fr = ln & 15, fg = ln >> 4;
  const int sr = ln >> 3, sc = ln & 7;   // staging row-in-8 / chunk
  const int sw = (sc ^ sr) * 8;          // swizzled SOURCE chunk (A, gl_lds)

  size_t aA[2], aB[2];
  int ldsw[2];
#pragma unroll
  for (int c = 0; c < 2; ++c) {
    int row = wv * 16 + c * 8 + sr;      // 0..127
    int p = row0 + row;
    int tok = ((p < row_end) ? pairs[p] : pairs[row0]) >> 1;
    aA[c] = (size_t)tok * DIMK + sw;                          // fp16 elems
    aB[c] = ((size_t)e * INTERN + n0 + row) * DIMK + sc * 8;  // fp32 elems, natural
    ldsw[c] = row * BK + (sc ^ sr) * 8;                       // swizzled DEST (B)
  }

  f32x4 acc1[4][2] = {};
  f32x4 acc3[4][2] = {};

  for (int k0 = 0; k0 < DIMK; k0 += BK) {
#pragma unroll
    for (int c = 0; c < 2; ++c)
      gl_lds16(xf + aA[c] + k0, &At[(wv * 16 + c * 8) * BK]);
#pragma unroll
    for (int c = 0; c < 2; ++c) {
      stage_cvt8(w1 + aB[c] + k0, &B1t[ldsw[c]]);
      stage_cvt8(w3 + aB[c] + k0, &B3t[ldsw[c]]);
    }
    __syncthreads();   // drains vmcnt (gl_lds) + lgkmcnt (ds_write)

#pragma unroll
    for (int kk = 0; kk < 2; ++kk) {
      half8 ah[4];
#pragma unroll
      for (int m = 0; m < 4; ++m) {
        int row = wm * 64 + m * 16 + fr;
        ah[m] = *reinterpret_cast<const half8*>(
            &At[row * BK + (((kk * 4 + fg) ^ (fr & 7)) * 8)]);
      }
#pragma unroll
      for (int n = 0; n < 2; ++n) {
        int row = wn * 32 + n * 16 + fr;
        int bo = row * BK + (((kk * 4 + fg) ^ (fr & 7)) * 8);
        half8 b1 = *reinterpret_cast<const half8*>(&B1t[bo]);
        half8 b3 = *reinterpret_cast<const half8*>(&B3t[bo]);
#pragma unroll
        for (int m = 0; m < 4; ++m) {
          acc1[m][n] = MFMAF16(ah[m], b1, acc1[m][n]);
          acc3[m][n] = MFMAF16(ah[m], b3, acc3[m][n]);
        }
      }
    }
    __syncthreads();
  }

  // ---- epilogue: h = silu(x1) * x3 -> fp16 ----
#pragma unroll
  for (int m = 0; m < 4; ++m)
#pragma unroll
    for (int n = 0; n < 2; ++n)
#pragma unroll
      for (int r = 0; r < 4; ++r) {
        int p = row0 + wm * 64 + m * 16 + fg * 4 + r;
        if (p < row_end) {
          int col = n0 + wn * 32 + n * 16 + fr;
          float a1 = acc1[m][n][r], a3 = acc3[m][n][r];
          float hv = (a1 / (1.0f + __expf(-a1))) * a3;
          hf[(size_t)p * INTERN + col] =
              __builtin_bit_cast(unsigned short, (_Float16)hv);
        }
      }
}

// ----------------------------------------------------- GEMM2: h @ w2, out ---
__global__ __launch_bounds__(NTG, 4) void gemm2_kernel(
    const float* __restrict__ w2, const int* __restrict__ offs,
    const int* __restrict__ pairs, const unsigned short* __restrict__ hf,
    float* __restrict__ out) {
  __shared__ __align__(16) unsigned short At[BM * BK];
  __shared__ __align__(16) unsigned short Bt[BN * BK];

  const int lid = xcd_swz((int)blockIdx.x, MAXRT * NT2);
  const int rt = lid % MAXRT, nt = lid / MAXRT;
  int e, row0, row_end;
  if (!find_tile(offs, rt, e, row0, row_end)) return;
  const int n0 = nt * BN;
  const int t = threadIdx.x;
  const int ln = t & 63;
  const int wv = t >> 6;
  const int wm = wv >> 2, wn = wv & 3;
  const int fr = ln & 15, fg = ln >> 4;
  const int sr = ln >> 3, sc = ln & 7;
  const int sw = (sc ^ sr) * 8;

  size_t aA[2], aB[2];
  int ldsw[2];
#pragma unroll
  for (int c = 0; c < 2; ++c) {
    int row = wv * 16 + c * 8 + sr;
    int p = row0 + row;
    int ar = (p < row_end) ? p : row0;
    aA[c] = (size_t)ar * INTERN + sw;                          // fp16 (h)
    aB[c] = ((size_t)e * DIMK + n0 + row) * INTERN + sc * 8;   // fp32 (w2)
    ldsw[c] = row * BK + (sc ^ sr) * 8;
  }

  f32x4 acc[4][2] = {};

  for (int k0 = 0; k0 < INTERN; k0 += BK) {
#pragma unroll
    for (int c = 0; c < 2; ++c)
      gl_lds16(hf + aA[c] + k0, &At[(wv * 16 + c * 8) * BK]);
#pragma unroll
    for (int c = 0; c < 2; ++c)
      stage_cvt8(w2 + aB[c] + k0, &Bt[ldsw[c]]);
    __syncthreads();

#pragma unroll
    for (int kk = 0; kk < 2; ++kk) {
      half8 ah[4];
#pragma unroll
      for (int m = 0; m < 4; ++m) {
        int row = wm * 64 + m * 16 + fr;
        ah[m] = *reinterpret_cast<const half8*>(
            &At[row * BK + (((kk * 4 + fg) ^ (fr & 7)) * 8)]);
      }
#pragma unroll
      for (int n = 0; n < 2; ++n) {
        int row = wn * 32 + n * 16 + fr;
        half8 b = *reinterpret_cast<const half8*>(
            &Bt[row * BK + (((kk * 4 + fg) ^ (fr & 7)) * 8)]);
#pragma unroll
        for (int m = 0; m < 4; ++m)
          acc[m][n] = MFMAF16(ah[m], b, acc[m][n]);
      }
    }
    __syncthreads();
  }

#pragma unroll
  for (int m = 0; m < 4; ++m)
#pragma unroll
    for (int n = 0; n < 2; ++n)
#pragma unroll
      for (int r = 0; r < 4; ++r) {
        int p = row0 + wm * 64 + m * 16 + fg * 4 + r;
        if (p < row_end) {
          int orow = pairs[p];
          out[(size_t)orow * DIMK + n0 + wn * 32 + n * 16 + fr] = acc[m][n][r];
        }
      }
}

// ------------------------------------------------------------------ launch ---
extern "C" void kernel_launch(void* const* d_in, const int* in_sizes, int n_in,
                              void* d_out, int out_size, void* d_ws, size_t ws_size,
                              hipStream_t stream) {
  const float* x  = (const float*)d_in[0];
  const int*   ei = (const int*)d_in[1];
  const float* w1 = (const float*)d_in[2];
  const float* w2 = (const float*)d_in[3];
  const float* w3 = (const float*)d_in[4];
  float* out = (float*)d_out;

  char* ws = (char*)d_ws;
  int* offs  = (int*)ws;                       // 9 ints
  int* pairs = (int*)(ws + 256);               // 8192 ints

  const size_t sz_x = (size_t)TTOK * DIMK;     // 4.19M elems
  size_t off = 65536;
  unsigned short* x_f = (unsigned short*)(ws + off); off += sz_x * 2;
  unsigned short* h_f = (unsigned short*)(ws + off);   // ~32 MB total ws use

  prep_kernel<<<XCVB + 1, NTH, 0, stream>>>(x, x_f, ei, offs, pairs);
  gemm1_kernel<<<MAXRT * NT1, NTG, 0, stream>>>(x_f, w1, w3, offs, pairs, h_f);
  gemm2_kernel<<<MAXRT * NT2, NTG, 0, stream>>>(w2, offs, pairs, h_f, out);
}

// Round 14
// 308.386 us; speedup vs baseline: 1.0887x; 1.0887x over previous
//
#include <hip/hip_runtime.h>

#define TTOK   4096
#define DIMK   1024
#define NEXP   8
#define INTERN 1408
#define NPAIRS 8192   // TTOK * TOPK

#define BM  128
#define BN  128
#define BK  64
#define NTH 256       // prep block size
#define NTG 512       // GEMM block size: 8 waves, 2x4 wave grid
#define MAXRT (NPAIRS / BM + NEXP - 1)   // 71 worst-case row tiles
#define NT1  (INTERN / BN)               // 11 n-tiles gemm1
#define NT2  (DIMK / BN)                 // 8 n-tiles gemm2

// prep partition: blocks [0,BX) convert x; [BX+k*BW, BX+(k+1)*BW) convert wk;
// block NCVT routes. Each block owns ONE array: branchless + ~4.6 iters/thread.
#define N8X (TTOK * DIMK / 8)            // 524288 16B-store units
#define N8W (NEXP * INTERN * DIMK / 8)   // 1441792
#define BX   444
#define BW   1218
#define NCVT (BX + 3 * BW)               // 4098

typedef __attribute__((ext_vector_type(8))) _Float16 half8;
typedef __attribute__((ext_vector_type(4))) float f32x4;

#define MFMAF16(a, b, c) __builtin_amdgcn_mfma_f32_16x16x32_f16((a), (b), (c), 0, 0, 0)

// async global->LDS, 16B/lane. LDS dest = wave-uniform base + lane*16 (linear);
// swizzle lives in the per-lane GLOBAL source address (m173 pattern).
__device__ __forceinline__ void gl_lds16(const void* g, void* l) {
  __builtin_amdgcn_global_load_lds(
      (const __attribute__((address_space(1))) void*)g,
      (__attribute__((address_space(3))) void*)l, 16, 0, 0);
}

// bijective XCD chunk swizzle (m204)
__device__ __forceinline__ int xcd_swz(int orig, int G) {
  int q = G >> 3, r = G & 7, x = orig & 7, p = orig >> 3;
  return (x < r ? x * (q + 1) : r * (q + 1) + (x - r) * q) + p;
}

// ------- prep: partitioned fp32->fp16 convert (4098 blocks) + route (1) ----
__device__ __forceinline__ void cvt_range(const float* __restrict__ src,
                                          unsigned short* __restrict__ dst,
                                          int n8, int tid, int stride) {
  const f32x4* s4 = reinterpret_cast<const f32x4*>(src);
  uint4* d4 = reinterpret_cast<uint4*>(dst);
  for (int i = tid; i < n8; i += stride) {
    f32x4 a = s4[2 * i], b = s4[2 * i + 1];
    uint4 o;
    o.x = __builtin_bit_cast(unsigned int, __builtin_amdgcn_cvt_pkrtz(a[0], a[1]));
    o.y = __builtin_bit_cast(unsigned int, __builtin_amdgcn_cvt_pkrtz(a[2], a[3]));
    o.z = __builtin_bit_cast(unsigned int, __builtin_amdgcn_cvt_pkrtz(b[0], b[1]));
    o.w = __builtin_bit_cast(unsigned int, __builtin_amdgcn_cvt_pkrtz(b[2], b[3]));
    d4[i] = o;
  }
}

__global__ __launch_bounds__(NTH) void prep_kernel(
    const float* __restrict__ x, const float* __restrict__ w1,
    const float* __restrict__ w3, const float* __restrict__ w2,
    unsigned short* __restrict__ xf, unsigned short* __restrict__ w1f,
    unsigned short* __restrict__ w3f, unsigned short* __restrict__ w2f,
    const int* __restrict__ ei, int* __restrict__ offs, int* __restrict__ pairs) {
  const int t = threadIdx.x;
  const int b = (int)blockIdx.x;

  if (b == NCVT) {
    // ---- routing block ----
    __shared__ int cnt[NEXP], base[NEXP], cur[NEXP], mode;
    if (t == 0) mode = 0;
    if (t < NEXP) cnt[t] = 0;
    __syncthreads();
    // width probe: odd 32-bit words all-zero => int64 input, else int32
    int any = 0;
    for (int i = t; i < NPAIRS / 2; i += NTH) any |= ei[2 * i + 1];
    if (any) atomicOr(&mode, 1);
    __syncthreads();
    const int m32 = mode;
    for (int i = t; i < NPAIRS; i += NTH) {
      int e = (m32 ? ei[i] : ei[2 * i]) & (NEXP - 1);
      atomicAdd(&cnt[e], 1);
    }
    __syncthreads();
    if (t == 0) {
      int s = 0;
      for (int e = 0; e < NEXP; ++e) { base[e] = s; offs[e] = s; s += cnt[e]; }
      offs[NEXP] = s;
    }
    __syncthreads();
    if (t < NEXP) cur[t] = base[t];
    __syncthreads();
    for (int i = t; i < NPAIRS; i += NTH) {
      int e = (m32 ? ei[i] : ei[2 * i]) & (NEXP - 1);
      int p = atomicAdd(&cur[e], 1);
      pairs[p] = i;   // pair id: token = i>>1, out row = i
    }
    return;
  }

  // ---- conversion: block-range partition, one array per block (uniform) ----
  if (b < BX) {
    cvt_range(x, xf, N8X, b * NTH + t, BX * NTH);
  } else if (b < BX + BW) {
    cvt_range(w1, w1f, N8W, (b - BX) * NTH + t, BW * NTH);
  } else if (b < BX + 2 * BW) {
    cvt_range(w3, w3f, N8W, (b - BX - BW) * NTH + t, BW * NTH);
  } else {
    cvt_range(w2, w2f, N8W, (b - BX - 2 * BW) * NTH + t, BW * NTH);
  }
}

// ------------------------------------------------------------ tile lookup ---
__device__ __forceinline__ bool find_tile(const int* __restrict__ offs, int rt,
                                          int &e, int &row0, int &row_end) {
  int cum = 0;
  for (int i = 0; i < NEXP; ++i) {
    int b = offs[i], en = offs[i + 1];
    int nt = (en - b + BM - 1) / BM;
    if (rt < cum + nt) { e = i; row0 = b + (rt - cum) * BM; row_end = en; return true; }
    cum += nt;
  }
  return false;
}

// -------------------------------------------------- GEMM1: x @ w1/w3, SiLU ---
// R10-proven structure: 512 threads = 8 waves (2x4), gl_lds for A and B with
// pre-swizzled source (0 bank conflicts, R8-verified), fp16 weights.
__global__ __launch_bounds__(NTG, 4) void gemm1_kernel(
    const unsigned short* __restrict__ xf, const unsigned short* __restrict__ w1f,
    const unsigned short* __restrict__ w3f, const int* __restrict__ offs,
    const int* __restrict__ pairs, unsigned short* __restrict__ hf) {
  __shared__ __align__(16) unsigned short At[BM * BK];
  __shared__ __align__(16) unsigned short B1t[BN * BK];
  __shared__ __align__(16) unsigned short B3t[BN * BK];

  const int lid = xcd_swz((int)blockIdx.x, MAXRT * NT1);
  const int rt = lid % MAXRT, nt = lid / MAXRT;   // rt fastest: XCD sweeps row
  int e, row0, row_end;                           // tiles vs L2-hot W slice
  if (!find_tile(offs, rt, e, row0, row_end)) return;
  const int n0 = nt * BN;
  const int t = threadIdx.x;
  const int ln = t & 63;
  const int wv = t >> 6;                 // wave 0..7
  const int wm = wv >> 2, wn = wv & 3;   // 2x4 wave grid over 128x128 out
  const int fr = ln & 15, fg = ln >> 4;
  const int sr = ln >> 3, sc = ln & 7;   // staging row-in-8 / chunk
  const int sw = (sc ^ sr) * 8;          // swizzled source chunk offset (halfs)

  size_t aA[2], aB[2];
#pragma unroll
  for (int c = 0; c < 2; ++c) {
    int row = wv * 16 + c * 8 + sr;      // 0..127
    int p = row0 + row;
    int tok = ((p < row_end) ? pairs[p] : pairs[row0]) >> 1;
    aA[c] = (size_t)tok * DIMK + sw;
    aB[c] = ((size_t)e * INTERN + n0 + row) * DIMK + sw;
  }

  f32x4 acc1[4][2] = {};
  f32x4 acc3[4][2] = {};

  for (int k0 = 0; k0 < DIMK; k0 += BK) {
#pragma unroll
    for (int c = 0; c < 2; ++c)
      gl_lds16(xf + aA[c] + k0, &At[(wv * 16 + c * 8) * BK]);
#pragma unroll
    for (int c = 0; c < 2; ++c)
      gl_lds16(w1f + aB[c] + k0, &B1t[(wv * 16 + c * 8) * BK]);
#pragma unroll
    for (int c = 0; c < 2; ++c)
      gl_lds16(w3f + aB[c] + k0, &B3t[(wv * 16 + c * 8) * BK]);
    __syncthreads();   // compiler drains vmcnt before s_barrier

#pragma unroll
    for (int kk = 0; kk < 2; ++kk) {
      half8 ah[4];
#pragma unroll
      for (int m = 0; m < 4; ++m) {
        int row = wm * 64 + m * 16 + fr;
        ah[m] = *reinterpret_cast<const half8*>(
            &At[row * BK + (((kk * 4 + fg) ^ (fr & 7)) * 8)]);
      }
#pragma unroll
      for (int n = 0; n < 2; ++n) {
        int row = wn * 32 + n * 16 + fr;
        int bo = row * BK + (((kk * 4 + fg) ^ (fr & 7)) * 8);
        half8 b1 = *reinterpret_cast<const half8*>(&B1t[bo]);
        half8 b3 = *reinterpret_cast<const half8*>(&B3t[bo]);
#pragma unroll
        for (int m = 0; m < 4; ++m) {
          acc1[m][n] = MFMAF16(ah[m], b1, acc1[m][n]);
          acc3[m][n] = MFMAF16(ah[m], b3, acc3[m][n]);
        }
      }
    }
    __syncthreads();
  }

  // ---- epilogue: h = silu(x1) * x3 -> fp16 ----
#pragma unroll
  for (int m = 0; m < 4; ++m)
#pragma unroll
    for (int n = 0; n < 2; ++n)
#pragma unroll
      for (int r = 0; r < 4; ++r) {
        int p = row0 + wm * 64 + m * 16 + fg * 4 + r;
        if (p < row_end) {
          int col = n0 + wn * 32 + n * 16 + fr;
          float a1 = acc1[m][n][r], a3 = acc3[m][n][r];
          float hv = (a1 / (1.0f + __expf(-a1))) * a3;
          hf[(size_t)p * INTERN + col] =
              __builtin_bit_cast(unsigned short, (_Float16)hv);
        }
      }
}

// ----------------------------------------------------- GEMM2: h @ w2, out ---
__global__ __launch_bounds__(NTG, 4) void gemm2_kernel(
    const unsigned short* __restrict__ w2f, const int* __restrict__ offs,
    const int* __restrict__ pairs, const unsigned short* __restrict__ hf,
    float* __restrict__ out) {
  __shared__ __align__(16) unsigned short At[BM * BK];
  __shared__ __align__(16) unsigned short Bt[BN * BK];

  const int lid = xcd_swz((int)blockIdx.x, MAXRT * NT2);
  const int rt = lid % MAXRT, nt = lid / MAXRT;
  int e, row0, row_end;
  if (!find_tile(offs, rt, e, row0, row_end)) return;
  const int n0 = nt * BN;
  const int t = threadIdx.x;
  const int ln = t & 63;
  const int wv = t >> 6;
  const int wm = wv >> 2, wn = wv & 3;
  const int fr = ln & 15, fg = ln >> 4;
  const int sr = ln >> 3, sc = ln & 7;
  const int sw = (sc ^ sr) * 8;

  size_t aA[2], aB[2];
#pragma unroll
  for (int c = 0; c < 2; ++c) {
    int row = wv * 16 + c * 8 + sr;
    int p = row0 + row;
    int ar = (p < row_end) ? p : row0;
    aA[c] = (size_t)ar * INTERN + sw;
    aB[c] = ((size_t)e * DIMK + n0 + row) * INTERN + sw;
  }

  f32x4 acc[4][2] = {};

  for (int k0 = 0; k0 < INTERN; k0 += BK) {
#pragma unroll
    for (int c = 0; c < 2; ++c)
      gl_lds16(hf + aA[c] + k0, &At[(wv * 16 + c * 8) * BK]);
#pragma unroll
    for (int c = 0; c < 2; ++c)
      gl_lds16(w2f + aB[c] + k0, &Bt[(wv * 16 + c * 8) * BK]);
    __syncthreads();

#pragma unroll
    for (int kk = 0; kk < 2; ++kk) {
      half8 ah[4];
#pragma unroll
      for (int m = 0; m < 4; ++m) {
        int row = wm * 64 + m * 16 + fr;
        ah[m] = *reinterpret_cast<const half8*>(
            &At[row * BK + (((kk * 4 + fg) ^ (fr & 7)) * 8)]);
      }
#pragma unroll
      for (int n = 0; n < 2; ++n) {
        int row = wn * 32 + n * 16 + fr;
        half8 b = *reinterpret_cast<const half8*>(
            &Bt[row * BK + (((kk * 4 + fg) ^ (fr & 7)) * 8)]);
#pragma unroll
        for (int m = 0; m < 4; ++m)
          acc[m][n] = MFMAF16(ah[m], b, acc[m][n]);
      }
    }
    __syncthreads();
  }

#pragma unroll
  for (int m = 0; m < 4; ++m)
#pragma unroll
    for (int n = 0; n < 2; ++n)
#pragma unroll
      for (int r = 0; r < 4; ++r) {
        int p = row0 + wm * 64 + m * 16 + fg * 4 + r;
        if (p < row_end) {
          int orow = pairs[p];
          out[(size_t)orow * DIMK + n0 + wn * 32 + n * 16 + fr] = acc[m][n][r];
        }
      }
}

// ------------------------------------------------------------------ launch ---
extern "C" void kernel_launch(void* const* d_in, const int* in_sizes, int n_in,
                              void* d_out, int out_size, void* d_ws, size_t ws_size,
                              hipStream_t stream) {
  const float* x  = (const float*)d_in[0];
  const int*   ei = (const int*)d_in[1];
  const float* w1 = (const float*)d_in[2];
  const float* w2 = (const float*)d_in[3];
  const float* w3 = (const float*)d_in[4];
  float* out = (float*)d_out;

  char* ws = (char*)d_ws;
  int* offs  = (int*)ws;                       // 9 ints
  int* pairs = (int*)(ws + 256);               // 8192 ints

  const size_t sz_x = (size_t)TTOK * DIMK;           // 4.19M
  const size_t sz_w = (size_t)NEXP * INTERN * DIMK;  // 11.53M
  size_t off = 65536;
  unsigned short* x_f  = (unsigned short*)(ws + off); off += sz_x * 2;
  unsigned short* w1_f = (unsigned short*)(ws + off); off += sz_w * 2;
  unsigned short* w3_f = (unsigned short*)(ws + off); off += sz_w * 2;
  unsigned short* w2_f = (unsigned short*)(ws + off); off += sz_w * 2;
  unsigned short* h_f  = (unsigned short*)(ws + off);   // ~101 MB total

  prep_kernel<<<NCVT + 1, NTH, 0, stream>>>(
      x, w1, w3, w2, x_f, w1_f, w3_f, w2_f, ei, offs, pairs);
  gemm1_kernel<<<MAXRT * NT1, NTG, 0, stream>>>(x_f, w1_f, w3_f, offs, pairs, h_f);
  gemm2_kernel<<<MAXRT * NT2, NTG, 0, stream>>>(w2_f, offs, pairs, h_f, out);
}